// Round 4
// baseline (956.972 us; speedup 1.0000x reference)
//
#include <hip/hip_runtime.h>
#include <hip/hip_fp16.h>

#define NN 100000
#define NE 1600000
#define D 64
#define BSHIFT 6
#define BNODES 64                         // nodes per bucket
#define NBUCK ((NN + BNODES - 1) / BNODES) // 1563
#define BCAP 2048                          // >> mean 1024 + 6 sigma (~32)
#define DPAD 68                            // LDS row pad: breaks 8-way ds_add bank conflict

// ---------------- fused edge pass: degree histogram + bucket scatter ----------------
// rec = (src << 6) | (dst & 63); bucket = dst >> 6
__global__ void k_edges(const int* __restrict__ src, const int* __restrict__ dst,
                        int* __restrict__ cnt, int* __restrict__ bcur,
                        unsigned* __restrict__ recs, int e) {
    int i = blockIdx.x * blockDim.x + threadIdx.x;
    if (i >= e) return;
    int s = src[i];
    int d = dst[i];
    atomicAdd(&cnt[d], 1);
    int bkt = d >> BSHIFT;
    int pos = atomicAdd(&bcur[bkt], 1);
    if (pos < BCAP)
        recs[(size_t)bkt * BCAP + pos] = ((unsigned)s << BSHIFT) | (unsigned)(d & (BNODES - 1));
}

// ---------------- projection fused with dinv, fp16 output: xw2 = half((x@W) * dinv) ----------------
// block = 256 threads = 4 rows x 64 cols
__global__ void k_xw2h(const float* __restrict__ x, const float* __restrict__ W,
                       const int* __restrict__ cnt, __half* __restrict__ xw2, int n) {
    __shared__ float sW[D][D];
    __shared__ float sx[4][D];
    int col = threadIdx.x & 63;
    int r   = threadIdx.x >> 6;

    for (int i = threadIdx.x; i < D * D; i += 256)
        sW[i >> 6][i & 63] = W[i];

    int row = blockIdx.x * 4 + r;
    if (row < n) sx[r][col] = x[row * D + col];
    __syncthreads();
    if (row >= n) return;

    float acc = 0.f;
#pragma unroll
    for (int k = 0; k < D; ++k)
        acc += sx[r][k] * sW[k][col];

    float di = rsqrtf((float)cnt[row] + 1.0f);   // +1 = self-loop
    xw2[(size_t)row * D + col] = __float2half(acc * di);
}

// ---------------- bucket accumulate: one WG per 64-node bucket ----------------
// out[d] = dinv[d] * (xw2[d] + sum_{s in N(d)} xw2[s]) + b
__global__ void k_accum(const unsigned* __restrict__ recs, const int* __restrict__ bcur,
                        const __half* __restrict__ xw2, const int* __restrict__ cnt,
                        const float* __restrict__ b, float* __restrict__ out, int n) {
    __shared__ float acc[BNODES][DPAD];   // 17.4 KB
    int bkt  = blockIdx.x;
    int tid  = threadIdx.x;
    int lane = tid & 63;
    int w    = tid >> 6;                  // wave 0..3

    // zero LDS
    for (int i = tid; i < BNODES * DPAD / 4; i += 256)
        ((float4*)acc)[i] = make_float4(0.f, 0.f, 0.f, 0.f);
    __syncthreads();

    int ne = bcur[bkt];
    if (ne > BCAP) ne = BCAP;
    const unsigned* rb = recs + (size_t)bkt * BCAP;

    int g  = lane >> 4;          // edge subgroup 0..3
    int c4 = (lane & 15) * 4;    // column base

    for (int e0 = w * 4; e0 < ne; e0 += 16) {   // 4 waves x 4 edges per iter
        int e = e0 + g;
        if (e < ne) {
            unsigned r = rb[e];
            int sn = r >> BSHIFT;
            int dl = r & (BNODES - 1);
            const __half* p = xw2 + (size_t)sn * D + c4;
            float2 ab = __half22float2(*(const __half2*)p);
            float2 cd = __half22float2(*(const __half2*)(p + 2));
            atomicAdd(&acc[dl][c4 + 0], ab.x);
            atomicAdd(&acc[dl][c4 + 1], ab.y);
            atomicAdd(&acc[dl][c4 + 2], cd.x);
            atomicAdd(&acc[dl][c4 + 3], cd.y);
        }
    }
    __syncthreads();

    int node0 = bkt * BNODES;
    float bl = b[lane];
    for (int r = w; r < BNODES; r += 4) {
        int node = node0 + r;
        if (node >= n) break;
        float di   = rsqrtf((float)cnt[node] + 1.0f);
        float self = __half2float(xw2[(size_t)node * D + lane]);
        out[(size_t)node * D + lane] = (acc[r][lane] + self) * di + bl;
    }
}

extern "C" void kernel_launch(void* const* d_in, const int* in_sizes, int n_in,
                              void* d_out, int out_size, void* d_ws, size_t ws_size,
                              hipStream_t stream) {
    const float* x  = (const float*)d_in[0];
    const int*   ei = (const int*)d_in[1];   // [2, E]: src row then dst row (int32)
    const float* W  = (const float*)d_in[2];
    const float* b  = (const float*)d_in[3];
    float* out = (float*)d_out;

    // workspace layout
    __half*   xw2  = (__half*)d_ws;                        // N*D halves = 12.8 MB
    int*      cnt  = (int*)(xw2 + (size_t)NN * D);         // N ints
    int*      bcur = cnt + NN;                             // NBUCK ints (adjacent -> one memset)
    unsigned* recs = (unsigned*)(bcur + NBUCK);            // NBUCK*BCAP uints = 12.8 MB

    const int* src = ei;
    const int* dst = ei + NE;

    hipMemsetAsync(cnt, 0, (size_t)(NN + NBUCK) * sizeof(int), stream);

    k_edges <<<(NE + 255) / 256, 256, 0, stream>>>(src, dst, cnt, bcur, recs, NE);
    k_xw2h  <<<(NN + 3) / 4, 256, 0, stream>>>(x, W, cnt, xw2, NN);
    k_accum <<<NBUCK, 256, 0, stream>>>(recs, bcur, xw2, cnt, b, out, NN);
}

// Round 5
// 257.402 us; speedup vs baseline: 3.7178x; 3.7178x over previous
//
#include <hip/hip_runtime.h>
#include <hip/hip_fp16.h>

#define NN 100000
#define NE 1600000
#define D 64
#define SCAN_B 256
#define NB_SCAN ((NN + SCAN_B - 1) / SCAN_B)   // 391
#define NSLICE 8
#define SLICE_N (NN / NSLICE)                  // 12500
#define ECHUNK 4096                             // edges per block in sliced passes
#define NCHUNK ((NE + ECHUNK - 1) / ECHUNK)    // 391

// ---------------- sliced histogram: block commits only dst in its XCD slice ----------------
__global__ void k_hist(const int* __restrict__ dst, int* __restrict__ cnt, int e) {
    int slice = blockIdx.x & 7;            // round-robin block->XCD => slice-local L2 atomics
    int chunk = blockIdx.x >> 3;
    int lo = slice * SLICE_N, hi = lo + SLICE_N;
    int base = chunk * ECHUNK + threadIdx.x * 4;
#pragma unroll
    for (int r = 0; r < 4; ++r) {
        int i = base + r * 1024;
        if (i + 3 < e) {
            int4 d = *(const int4*)(dst + i);
            if (d.x >= lo && d.x < hi) atomicAdd(&cnt[d.x], 1);
            if (d.y >= lo && d.y < hi) atomicAdd(&cnt[d.y], 1);
            if (d.z >= lo && d.z < hi) atomicAdd(&cnt[d.z], 1);
            if (d.w >= lo && d.w < hi) atomicAdd(&cnt[d.w], 1);
        } else {
            for (int j = i; j < e && j < i + 4; ++j) {
                int d = dst[j];
                if (d >= lo && d < hi) atomicAdd(&cnt[d], 1);
            }
        }
    }
}

// ---------------- 3-phase exclusive scan of cnt -> rowstart, cursor ----------------
__global__ void k_scan_block(const int* __restrict__ cnt, int* __restrict__ excl,
                             int* __restrict__ bsum, int n) {
    __shared__ int tmp[SCAN_B];
    int tid = threadIdx.x;
    int i = blockIdx.x * SCAN_B + tid;
    int v = (i < n) ? cnt[i] : 0;
    tmp[tid] = v;
    __syncthreads();
    for (int off = 1; off < SCAN_B; off <<= 1) {
        int t = (tid >= off) ? tmp[tid - off] : 0;
        __syncthreads();
        tmp[tid] += t;
        __syncthreads();
    }
    if (i < n) excl[i] = tmp[tid] - v;
    if (tid == SCAN_B - 1) bsum[blockIdx.x] = tmp[tid];
}

__global__ void k_scan_bsum(int* __restrict__ bsum, int nb) {
    __shared__ int tmp[512];
    int tid = threadIdx.x;
    int v = (tid < nb) ? bsum[tid] : 0;
    tmp[tid] = v;
    __syncthreads();
    for (int off = 1; off < 512; off <<= 1) {
        int t = (tid >= off) ? tmp[tid - off] : 0;
        __syncthreads();
        tmp[tid] += t;
        __syncthreads();
    }
    if (tid < nb) bsum[tid] = tmp[tid] - v;
}

__global__ void k_scan_add(int* __restrict__ excl, int* __restrict__ cursor,
                           const int* __restrict__ bsum, int n) {
    int i = blockIdx.x * blockDim.x + threadIdx.x;
    if (i < n) {
        int r = excl[i] + bsum[blockIdx.x];   // blockDim == SCAN_B
        excl[i] = r;
        cursor[i] = r;
    }
}

// ---------------- projection fused with dinv, fp16 out: xw2 = half((x@W) * dinv) ----------------
__global__ void k_xw2h(const float* __restrict__ x, const float* __restrict__ W,
                       const int* __restrict__ cnt, __half* __restrict__ xw2, int n) {
    __shared__ float sW[D][D];
    __shared__ float sx[4][D];
    int col = threadIdx.x & 63;
    int r   = threadIdx.x >> 6;

    for (int i = threadIdx.x; i < D * D; i += 256)
        sW[i >> 6][i & 63] = W[i];

    int row = blockIdx.x * 4 + r;
    if (row < n) sx[r][col] = x[row * D + col];
    __syncthreads();
    if (row >= n) return;

    float acc = 0.f;
#pragma unroll
    for (int k = 0; k < D; ++k)
        acc += sx[r][k] * sW[k][col];

    float di = rsqrtf((float)cnt[row] + 1.0f);   // +1 = self-loop
    xw2[(size_t)row * D + col] = __float2half(acc * di);
}

// ---------------- sliced CSR build: place src ids in dst-CSR order ----------------
__global__ void k_build(const int* __restrict__ src, const int* __restrict__ dst,
                        int* __restrict__ cursor, int* __restrict__ recs, int e) {
    int slice = blockIdx.x & 7;
    int chunk = blockIdx.x >> 3;
    int lo = slice * SLICE_N, hi = lo + SLICE_N;
    int base = chunk * ECHUNK + threadIdx.x * 4;
#pragma unroll
    for (int r = 0; r < 4; ++r) {
        int i = base + r * 1024;
        if (i + 3 < e) {
            int4 d = *(const int4*)(dst + i);
            int4 s = *(const int4*)(src + i);
            if (d.x >= lo && d.x < hi) recs[atomicAdd(&cursor[d.x], 1)] = s.x;
            if (d.y >= lo && d.y < hi) recs[atomicAdd(&cursor[d.y], 1)] = s.y;
            if (d.z >= lo && d.z < hi) recs[atomicAdd(&cursor[d.z], 1)] = s.z;
            if (d.w >= lo && d.w < hi) recs[atomicAdd(&cursor[d.w], 1)] = s.w;
        } else {
            for (int j = i; j < e && j < i + 4; ++j) {
                int d = dst[j];
                if (d >= lo && d < hi) recs[atomicAdd(&cursor[d], 1)] = src[j];
            }
        }
    }
}

// ---------------- gather-accumulate: one wave per node ----------------
// out[d] = dinv[d] * (xw2[d] + sum_{s in N(d)} xw2[s]) + b
__global__ void k_gather(const int* __restrict__ recs, const int* __restrict__ rowstart,
                         const int* __restrict__ cnt, const __half* __restrict__ xw2,
                         const float* __restrict__ b, float* __restrict__ out, int n) {
    int wid  = (blockIdx.x * blockDim.x + threadIdx.x) >> 6;   // node id
    int lane = threadIdx.x & 63;                                // column
    if (wid >= n) return;

    int base = __builtin_amdgcn_readfirstlane(rowstart[wid]);
    int k    = __builtin_amdgcn_readfirstlane(cnt[wid]);

    float acc = __half2float(xw2[(size_t)wid * D + lane]);   // self-loop (dinv-scaled)

    int i = 0;
    for (; i + 4 <= k; i += 4) {
        int s0 = recs[base + i + 0];
        int s1 = recs[base + i + 1];
        int s2 = recs[base + i + 2];
        int s3 = recs[base + i + 3];
        float v0 = __half2float(xw2[(size_t)s0 * D + lane]);
        float v1 = __half2float(xw2[(size_t)s1 * D + lane]);
        float v2 = __half2float(xw2[(size_t)s2 * D + lane]);
        float v3 = __half2float(xw2[(size_t)s3 * D + lane]);
        acc += (v0 + v1) + (v2 + v3);
    }
    for (; i < k; ++i)
        acc += __half2float(xw2[(size_t)recs[base + i] * D + lane]);

    float di = rsqrtf((float)k + 1.0f);
    out[(size_t)wid * D + lane] = acc * di + b[lane];
}

extern "C" void kernel_launch(void* const* d_in, const int* in_sizes, int n_in,
                              void* d_out, int out_size, void* d_ws, size_t ws_size,
                              hipStream_t stream) {
    const float* x  = (const float*)d_in[0];
    const int*   ei = (const int*)d_in[1];   // [2, E]: src row then dst row (int32)
    const float* W  = (const float*)d_in[2];
    const float* b  = (const float*)d_in[3];
    float* out = (float*)d_out;

    // workspace layout
    __half* xw2      = (__half*)d_ws;                       // N*D halves = 12.8 MB
    int*    cnt      = (int*)(xw2 + (size_t)NN * D);        // N
    int*    rowstart = cnt + NN;                            // N
    int*    cursor   = rowstart + NN;                       // N
    int*    bsum     = cursor + NN;                         // 512
    int*    recs     = bsum + 512;                          // E = 6.4 MB

    const int* src = ei;
    const int* dst = ei + NE;

    hipMemsetAsync(cnt, 0, (size_t)NN * sizeof(int), stream);

    k_hist      <<<NCHUNK * NSLICE, 256, 0, stream>>>(dst, cnt, NE);

    k_scan_block<<<NB_SCAN, SCAN_B, 0, stream>>>(cnt, rowstart, bsum, NN);
    k_scan_bsum <<<1, 512, 0, stream>>>(bsum, NB_SCAN);
    k_scan_add  <<<NB_SCAN, SCAN_B, 0, stream>>>(rowstart, cursor, bsum, NN);

    k_xw2h      <<<(NN + 3) / 4, 256, 0, stream>>>(x, W, cnt, xw2, NN);
    k_build     <<<NCHUNK * NSLICE, 256, 0, stream>>>(src, dst, cursor, recs, NE);

    long long tot = (long long)NN * 64;
    k_gather    <<<(int)((tot + 255) / 256), 256, 0, stream>>>(recs, rowstart, cnt, xw2, b, out, NN);
}